// Round 11
// baseline (277.770 us; speedup 1.0000x reference)
//
#include <hip/hip_runtime.h>
#include <stdint.h>

typedef unsigned short u16;
typedef unsigned int u32;
typedef __attribute__((ext_vector_type(8))) short short8;
typedef __attribute__((ext_vector_type(4))) float f32x4;
typedef __attribute__((ext_vector_type(16))) float f32x16;

#define DEVI static __device__ __forceinline__

DEVI u16 f2bf(float f) {
  union { float f; u32 u; } v; v.f = f;
  u32 r = v.u + 0x7FFFu + ((v.u >> 16) & 1u);
  return (u16)(r >> 16);
}

DEVI u32 pack2bf(float lo, float hi) {
  return (u32)f2bf(lo) | ((u32)f2bf(hi) << 16);
}

// fast pack: round-half-up bf16 pair via v_perm_b32 (3 VALU ops / 2 elements)
DEVI u32 pack2bf_fast(float lo, float hi) {
  union { float f; u32 u; } a, b;
  a.f = lo; b.f = hi;
  return __builtin_amdgcn_perm(b.u + 0x8000u, a.u + 0x8000u, 0x07060302u);
}

// single-instruction RNE bf16 pair pack
DEVI u32 cvtpk(float lo, float hi) {
  u32 r;
  asm("v_cvt_pk_bf16_f32 %0, %1, %2" : "=v"(r) : "v"(lo), "v"(hi));
  return r;
}

// lane[0:31] of b <-> lane[32:63] of a  (both updated)
DEVI void swap32(u32& a, u32& b) {
  asm("v_permlane32_swap_b32 %0, %1" : "+v"(a), "+v"(b));
}

DEVI void gload_lds16(const u16* g, u16* l) {
  __builtin_amdgcn_global_load_lds((const __attribute__((address_space(1))) void*)g,
                                   (__attribute__((address_space(3))) void*)l, 16, 0, 0);
}

// chunk swizzle: 16B chunk 'chunk' of row r lives at slot chunk^(r&7)^((r>>3)&3).
DEVI int sw8(int chunk, int r) { return ((chunk ^ (r & 7) ^ ((r >> 3) & 3)) * 8); }

// ---------------- prep: weight transpose f32->bf16 (4 weights) + input cvt f32->bf16 (3 inputs)
__global__ __launch_bounds__(256) void prep(const float* __restrict__ wq, const float* __restrict__ wk,
                                            const float* __restrict__ wv, const float* __restrict__ wo,
                                            u16* __restrict__ wqT, u16* __restrict__ wkT,
                                            u16* __restrict__ wvT, u16* __restrict__ woT,
                                            const float* __restrict__ xq, const float* __restrict__ xk,
                                            const float* __restrict__ xv,
                                            u16* __restrict__ qb, u16* __restrict__ kb,
                                            u16* __restrict__ vb) {
  const int bid = blockIdx.x;
  const int t = threadIdx.x;
  if (bid < 1024) {
    int z = bid >> 8, tl = bid & 255;
    const float* src = z == 0 ? wq : z == 1 ? wk : z == 2 ? wv : wo;
    u16* dst = z == 0 ? wqT : z == 1 ? wkT : z == 2 ? wvT : woT;
    __shared__ float tile[32][33];
    int tx = t & 31, ty = t >> 5;
    int bx = (tl & 15) * 32, by = (tl >> 4) * 32;
#pragma unroll
    for (int i = 0; i < 32; i += 8)
      tile[ty + i][tx] = src[(size_t)(by + ty + i) * 512 + bx + tx];
    __syncthreads();
#pragma unroll
    for (int i = 0; i < 32; i += 8)
      dst[(size_t)(bx + ty + i) * 512 + by + tx] = f2bf(tile[tx][ty + i]);
  } else {
    int cid = bid - 1024;
    int which = cid >> 11, chunk = cid & 2047;
    const float* src = which == 0 ? xq : which == 1 ? xk : xv;
    u16* dst = which == 0 ? qb : which == 1 ? kb : vb;
    size_t base = (size_t)chunk * 2048 + t * 8;
    float4 f0 = *(const float4*)(src + base);
    float4 f1 = *(const float4*)(src + base + 4);
    uint4 pk;
    pk.x = pack2bf_fast(f0.x, f0.y);
    pk.y = pack2bf_fast(f0.z, f0.w);
    pk.z = pack2bf_fast(f1.x, f1.y);
    pk.w = pack2bf_fast(f1.z, f1.w);
    *(uint4*)(dst + base) = pk;
  }
}

// ---------------- fused QKV GEMM, 64x128 tile (R10 version, measured fine) ----------------
__global__ __launch_bounds__(256, 6) void gemm_qkv(
    const u16* __restrict__ A0, const u16* __restrict__ A1, const u16* __restrict__ A2,
    const u16* __restrict__ W0, const u16* __restrict__ W1, const u16* __restrict__ W2,
    const float* __restrict__ b0, const float* __restrict__ b1, const float* __restrict__ b2,
    u16* __restrict__ oq, u16* __restrict__ ok, u16* __restrict__ vt, float qscale) {
  const int z = blockIdx.z;
  const u16* A = z == 0 ? A0 : z == 1 ? A1 : A2;
  const u16* WT = z == 0 ? W0 : z == 1 ? W1 : W2;
  const float* bias = z == 0 ? b0 : z == 1 ? b1 : b2;
  const float sc = z == 0 ? qscale : 1.0f;

  __shared__ __align__(16) u16 As[64 * 64];   // 8 KB
  __shared__ __align__(16) u16 Bs[128 * 64];  // 16 KB
  const int t = threadIdx.x;
  const int w = t >> 6, lane = t & 63, quad = lane >> 4, li = lane & 15;
  const int m0 = blockIdx.x * 64, n0 = blockIdx.y * 128;
  const int wm = (w >> 1) * 32, wn = (w & 1) * 64;

  f32x4 zv = {0.f, 0.f, 0.f, 0.f};
  f32x4 acc[2][4];
#pragma unroll
  for (int mi = 0; mi < 2; mi++)
#pragma unroll
    for (int ni = 0; ni < 4; ni++) acc[mi][ni] = zv;

  for (int it = 0; it < 8; it++) {
    const int k0 = it * 64;
#pragma unroll
    for (int p = 0; p < 2; p++) {
      int s = p * 256 + t;
      int r = s >> 3, c8 = s & 7;
      gload_lds16(A + (size_t)(m0 + r) * 512 + k0 + sw8(c8, r), &As[(p * 256 + w * 64) * 8]);
    }
#pragma unroll
    for (int p = 0; p < 4; p++) {
      int s = p * 256 + t;
      int r = s >> 3, c8 = s & 7;
      gload_lds16(WT + (size_t)(n0 + r) * 512 + k0 + sw8(c8, r), &Bs[(p * 256 + w * 64) * 8]);
    }
    __syncthreads();
#pragma unroll
    for (int ks = 0; ks < 2; ks++) {
      short8 af[2], bf[4];
#pragma unroll
      for (int mi = 0; mi < 2; mi++) {
        int r = wm + mi * 16 + li;
        af[mi] = *(const short8*)&As[r * 64 + sw8(ks * 4 + quad, r)];
      }
#pragma unroll
      for (int ni = 0; ni < 4; ni++) {
        int r = wn + ni * 16 + li;
        bf[ni] = *(const short8*)&Bs[r * 64 + sw8(ks * 4 + quad, r)];
      }
#pragma unroll
      for (int mi = 0; mi < 2; mi++)
#pragma unroll
        for (int ni = 0; ni < 4; ni++)
          acc[mi][ni] = __builtin_amdgcn_mfma_f32_16x16x32_bf16(af[mi], bf[ni], acc[mi][ni], 0, 0, 0);
    }
    __syncthreads();
  }

  float bv[4];
#pragma unroll
  for (int ni = 0; ni < 4; ni++) bv[ni] = bias[n0 + wn + ni * 16 + li];

  if (z < 2) {
    u16* out = z == 0 ? oq : ok;
#pragma unroll
    for (int mi = 0; mi < 2; mi++)
#pragma unroll
      for (int ni = 0; ni < 4; ni++)
#pragma unroll
        for (int r = 0; r < 4; r++) {
          int row = m0 + wm + mi * 16 + quad * 4 + r;
          int col = n0 + wn + ni * 16 + li;
          out[(size_t)row * 512 + col] = f2bf((acc[mi][ni][r] + bv[ni]) * sc);
        }
  } else {
    // V: write directly in VT [b, h, d, 2048] layout
#pragma unroll
    for (int mi = 0; mi < 2; mi++)
#pragma unroll
      for (int ni = 0; ni < 4; ni++) {
        int col = n0 + wn + ni * 16 + li;
        int h = col >> 6, dd = col & 63;
        int row0 = m0 + wm + mi * 16 + quad * 4;
        int bb = row0 >> 11, l0 = row0 & 2047;
        uint2 dw;
        dw.x = pack2bf(acc[mi][ni][0] + bv[ni], acc[mi][ni][1] + bv[ni]);
        dw.y = pack2bf(acc[mi][ni][2] + bv[ni], acc[mi][ni][3] + bv[ni]);
        *(uint2*)&vt[((size_t)((bb * 8 + h) * 64 + dd)) * 2048 + l0] = dw;
      }
  }
}

// ---------------- final projection GEMM, 64x64 tile (R10 version) ----------------
__global__ __launch_bounds__(256, 4) void gemm_out(const u16* __restrict__ A,
                                                   const u16* __restrict__ WT,
                                                   const float* __restrict__ bias,
                                                   float* __restrict__ out) {
  __shared__ __align__(16) u16 As[64 * 64];  // 8 KB
  __shared__ __align__(16) u16 Bs[64 * 64];  // 8 KB
  const int t = threadIdx.x;
  const int w = t >> 6, lane = t & 63, quad = lane >> 4, li = lane & 15;
  const int m0 = blockIdx.x * 64, n0 = blockIdx.y * 64;
  const int wm = (w >> 1) * 32, wn = (w & 1) * 32;

  f32x4 zv = {0.f, 0.f, 0.f, 0.f};
  f32x4 acc[2][2];
#pragma unroll
  for (int mi = 0; mi < 2; mi++)
#pragma unroll
    for (int ni = 0; ni < 2; ni++) acc[mi][ni] = zv;

  for (int it = 0; it < 8; it++) {
    const int k0 = it * 64;
#pragma unroll
    for (int p = 0; p < 2; p++) {
      int s = p * 256 + t;
      int r = s >> 3, c8 = s & 7;
      gload_lds16(A + (size_t)(m0 + r) * 512 + k0 + sw8(c8, r), &As[(p * 256 + w * 64) * 8]);
    }
#pragma unroll
    for (int p = 0; p < 2; p++) {
      int s = p * 256 + t;
      int r = s >> 3, c8 = s & 7;
      gload_lds16(WT + (size_t)(n0 + r) * 512 + k0 + sw8(c8, r), &Bs[(p * 256 + w * 64) * 8]);
    }
    __syncthreads();
#pragma unroll
    for (int ks = 0; ks < 2; ks++) {
      short8 af[2], bf[2];
#pragma unroll
      for (int mi = 0; mi < 2; mi++) {
        int r = wm + mi * 16 + li;
        af[mi] = *(const short8*)&As[r * 64 + sw8(ks * 4 + quad, r)];
      }
#pragma unroll
      for (int ni = 0; ni < 2; ni++) {
        int r = wn + ni * 16 + li;
        bf[ni] = *(const short8*)&Bs[r * 64 + sw8(ks * 4 + quad, r)];
      }
#pragma unroll
      for (int mi = 0; mi < 2; mi++)
#pragma unroll
        for (int ni = 0; ni < 2; ni++)
          acc[mi][ni] = __builtin_amdgcn_mfma_f32_16x16x32_bf16(af[mi], bf[ni], acc[mi][ni], 0, 0, 0);
    }
    __syncthreads();
  }

  float bv[2];
#pragma unroll
  for (int ni = 0; ni < 2; ni++) bv[ni] = bias[n0 + wn + ni * 16 + li];
#pragma unroll
  for (int mi = 0; mi < 2; mi++)
#pragma unroll
    for (int ni = 0; ni < 2; ni++)
#pragma unroll
      for (int r = 0; r < 4; r++) {
        int row = m0 + wm + mi * 16 + quad * 4 + r;
        int col = n0 + wn + ni * 16 + li;
        out[(size_t)row * 512 + col] = acc[mi][ni][r] + bv[ni];
      }
}

// ---------------- attention v9: LDS-FREE, barrier-free, K-split x2 ----------------
// Every K/V fragment loaded directly from global (per-lane short8 at the exact offsets
// the LDS path reconstructed). Block's 4 waves read identical 16KB tiles -> L1-served;
// K/V panels L3-resident. Zero LDS / zero barriers: waves fully independent, drift to
// fill each other's dependency bubbles. K-split s in {0,1} -> 1024 blocks = 4 blocks/CU
// = 16 waves/CU (2x R10). Partial f32 O^T + L combined by reduce_o (R1-proven).
__global__ __launch_bounds__(256, 4) void attn(const u16* __restrict__ Qp,
                                               const u16* __restrict__ Kp,
                                               const u16* __restrict__ VT,
                                               float* __restrict__ Op,
                                               float* __restrict__ Lb) {
  const int t = threadIdx.x;
  const int w = t >> 6, lane = t & 63, qn = lane & 31, hi = lane >> 5;
  const int b = blockIdx.z, h = blockIdx.y >> 1, s = blockIdx.y & 1;
  const int qrow = blockIdx.x * 128 + w * 32 + qn;

  // Q fragments (one-time): B[k=d][n=q]
  short8 qf[4];
  {
    const u16* qg = Qp + (size_t)(b * 2048 + qrow) * 512 + h * 64 + hi * 8;
#pragma unroll
    for (int ks4 = 0; ks4 < 4; ks4++) qf[ks4] = *(const short8*)(qg + ks4 * 16);
  }

  f32x16 o[2];
#pragma unroll
  for (int dt = 0; dt < 2; dt++)
#pragma unroll
    for (int r = 0; r < 16; r++) o[dt][r] = 0.f;
  float lsum = 0.f;

  // K: row (b*2048 + s*1024 + kj), cols h*64 + ks4*16 + hi*8
  const u16* kb_ = Kp + ((size_t)(b * 2048 + s * 1024)) * 512 + h * 64 + hi * 8;
  // V^T: row (b*8+h)*64 + dt*32 + qn, cols s*1024 + k0 + kjt*32 + {0,16} + hi*8
  const u16* vb_ = VT + ((size_t)((b * 8 + h) * 64 + qn)) * 2048 + s * 1024 + hi * 8;

#pragma unroll 1
  for (int kt = 0; kt < 16; kt++) {
    const int k0 = kt * 64;
#pragma unroll
    for (int kjt = 0; kjt < 2; kjt++) {
      // S^T = K·Q^T : lane qn holds column q=qrow, rows kj = kjt*32 + (r&3)+8*(r>>2)+4*hi
      const u16* krow = kb_ + (size_t)(k0 + kjt * 32 + qn) * 512;
      f32x16 st;
#pragma unroll
      for (int r = 0; r < 16; r++) st[r] = 0.f;
      st = __builtin_amdgcn_mfma_f32_32x32x16_bf16(*(const short8*)(krow), qf[0], st, 0, 0, 0);
      st = __builtin_amdgcn_mfma_f32_32x32x16_bf16(*(const short8*)(krow + 16), qf[1], st, 0, 0, 0);
      st = __builtin_amdgcn_mfma_f32_32x32x16_bf16(*(const short8*)(krow + 32), qf[2], st, 0, 0, 0);
      st = __builtin_amdgcn_mfma_f32_32x32x16_bf16(*(const short8*)(krow + 48), qf[3], st, 0, 0, 0);

      // p = exp2(s); pack pairs to bf16 (RNE) in-register  (identical to v6)
      u32 pk[8];
#pragma unroll
      for (int i = 0; i < 8; i++) {
        float p0 = __builtin_amdgcn_exp2f(st[2 * i]);
        float p1 = __builtin_amdgcn_exp2f(st[2 * i + 1]);
        lsum += p0 + p1;
        pk[i] = cvtpk(p0, p1);
      }
      u32 a0 = pk[0], a2 = pk[2]; swap32(a0, a2);
      u32 a1 = pk[1], a3 = pk[3]; swap32(a1, a3);
      u32 c0 = pk[4], c2 = pk[6]; swap32(c0, c2);
      u32 c1 = pk[5], c3 = pk[7]; swap32(c1, c3);
      union { u32 u[4]; short8 s8; } pa, pb;
      pa.u[0] = a0; pa.u[1] = a1; pa.u[2] = a2; pa.u[3] = a3;  // kj slice kjt*2   (local 0..15)
      pb.u[0] = c0; pb.u[1] = c1; pb.u[2] = c2; pb.u[3] = c3;  // kj slice kjt*2+1 (local 16..31)

      // O^T += V^T · P^T  (V rows d = dt*32+qn; dt stride = 32*2048 u16)
      const u16* vcol = vb_ + k0 + kjt * 32;
      o[0] = __builtin_amdgcn_mfma_f32_32x32x16_bf16(*(const short8*)(vcol), pa.s8, o[0], 0, 0, 0);
      o[1] = __builtin_amdgcn_mfma_f32_32x32x16_bf16(*(const short8*)(vcol + 32 * 2048), pa.s8, o[1], 0, 0, 0);
      o[0] = __builtin_amdgcn_mfma_f32_32x32x16_bf16(*(const short8*)(vcol + 16), pb.s8, o[0], 0, 0, 0);
      o[1] = __builtin_amdgcn_mfma_f32_32x32x16_bf16(*(const short8*)(vcol + 32 * 2048 + 16), pb.s8, o[1], 0, 0, 0);
    }
  }

  // epilogue: store partial O^T (f32, [d][q] layout, coalesced) + partial l
  float l = lsum + __shfl_xor(lsum, 32);
  if (hi == 0) Lb[((size_t)((b * 8 + h) * 2 + s)) * 2048 + qrow] = l;
#pragma unroll
  for (int dt = 0; dt < 2; dt++)
#pragma unroll
    for (int r = 0; r < 16; r++) {
      int d = dt * 32 + (r & 3) + 8 * (r >> 2) + 4 * hi;
      Op[((size_t)(((b * 8 + h) * 2 + s) * 64 + d)) * 2048 + qrow] = o[dt][r];
    }
}

// ---------------- combine K-splits, normalize, transpose [d][q] -> ctx [q][h*64+d] ----------------
__global__ __launch_bounds__(256) void reduce_o(const float* __restrict__ Op,
                                                const float* __restrict__ Lb,
                                                u16* __restrict__ ctx) {
  __shared__ float tile[64 * 65];  // [d][q], pitch 65
  const int t = threadIdx.x;
  const int b = blockIdx.z, h = blockIdx.y, q0 = blockIdx.x * 64;
  {
    int d = t >> 2, qc = (t & 3) * 16;
    const float* p0 = Op + ((size_t)(((b * 8 + h) * 2 + 0) * 64 + d)) * 2048 + q0 + qc;
    const float* p1 = Op + ((size_t)(((b * 8 + h) * 2 + 1) * 64 + d)) * 2048 + q0 + qc;
#pragma unroll
    for (int i = 0; i < 4; i++) {
      float4 a = *(const float4*)(p0 + i * 4);
      float4 c = *(const float4*)(p1 + i * 4);
      float4 v;
      v.x = a.x + c.x; v.y = a.y + c.y; v.z = a.z + c.z; v.w = a.w + c.w;
      *(float4*)&tile[d * 65 + qc + i * 4] = v;
    }
  }
  __syncthreads();
  {
    int q = t >> 2, dc = (t & 3) * 16;
    float l0 = Lb[((size_t)((b * 8 + h) * 2 + 0)) * 2048 + q0 + q];
    float l1 = Lb[((size_t)((b * 8 + h) * 2 + 1)) * 2048 + q0 + q];
    float inv = 1.0f / (l0 + l1);
    u32 pk[8];
#pragma unroll
    for (int i = 0; i < 8; i++) {
      float v0 = tile[(dc + i * 2) * 65 + q] * inv;
      float v1 = tile[(dc + i * 2 + 1) * 65 + q] * inv;
      pk[i] = pack2bf(v0, v1);
    }
    u16* dst = ctx + (size_t)(b * 2048 + q0 + q) * 512 + h * 64 + dc;
    *(uint4*)dst = *(uint4*)&pk[0];
    *(uint4*)(dst + 8) = *(uint4*)&pk[4];
  }
}

extern "C" void kernel_launch(void* const* d_in, const int* in_sizes, int n_in,
                              void* d_out, int out_size, void* d_ws, size_t ws_size,
                              hipStream_t stream) {
  const float* query = (const float*)d_in[0];
  const float* key_ = (const float*)d_in[1];
  const float* value = (const float*)d_in[2];
  const float* wq = (const float*)d_in[3];
  const float* bq = (const float*)d_in[4];
  const float* wk = (const float*)d_in[5];
  const float* bk = (const float*)d_in[6];
  const float* wv = (const float*)d_in[7];
  const float* bv = (const float*)d_in[8];
  const float* wo = (const float*)d_in[9];
  const float* bo = (const float*)d_in[10];

  char* ws = (char*)d_ws;
  const size_t SZ_W = (size_t)512 * 512 * 2;   // 512 KB
  const size_t SZ_X = (size_t)8192 * 512 * 2;  // 8 MB
  u16* wqT = (u16*)(ws);
  u16* wkT = (u16*)(ws + SZ_W);
  u16* wvT = (u16*)(ws + 2 * SZ_W);
  u16* woT = (u16*)(ws + 3 * SZ_W);
  u16* Qp = (u16*)(ws + 4 * SZ_W);
  u16* Kp = (u16*)(ws + 4 * SZ_W + SZ_X);
  u16* VTp = (u16*)(ws + 4 * SZ_W + 2 * SZ_X);
  u16* Qb = (u16*)(ws + 4 * SZ_W + 3 * SZ_X);  // bf16 pre-converted inputs (dead after gemm_qkv)
  u16* Kb = (u16*)(ws + 4 * SZ_W + 4 * SZ_X);
  u16* Vb = (u16*)(ws + 4 * SZ_W + 5 * SZ_X);
  // Opb aliases the dead Qb/Kb/Vb region (attn runs after gemm_qkv) -> footprint 58.5 MB
  float* Opb = (float*)(ws + 4 * SZ_W + 3 * SZ_X);                      // 32 MB
  float* Lb = (float*)(ws + 4 * SZ_W + 3 * SZ_X + ((size_t)32 << 20));  // 512 KB
  u16* ctx = Qp;  // reduce_o writes ctx over Qp (Qp dead after attn)

  const float C1 = 0.125f * 1.44269504088896f;  // softmax scale * log2(e), folded into Q

  prep<<<dim3(7168), 256, 0, stream>>>(wq, wk, wv, wo, wqT, wkT, wvT, woT,
                                       query, key_, value, Qb, Kb, Vb);
  gemm_qkv<<<dim3(128, 4, 3), 256, 0, stream>>>(Qb, Kb, Vb, wqT, wkT, wvT,
                                                bq, bk, bv, Qp, Kp, VTp, C1);
  attn<<<dim3(16, 16, 4), 256, 0, stream>>>(Qp, Kp, VTp, Opb, Lb);
  reduce_o<<<dim3(32, 8, 4), 256, 0, stream>>>(Opb, Lb, ctx);
  gemm_out<<<dim3(128, 8), 256, 0, stream>>>(ctx, woT, bo, (float*)d_out);
}

// Round 12
// 182.323 us; speedup vs baseline: 1.5235x; 1.5235x over previous
//
#include <hip/hip_runtime.h>
#include <stdint.h>

typedef unsigned short u16;
typedef unsigned int u32;
typedef __attribute__((ext_vector_type(8))) short short8;
typedef __attribute__((ext_vector_type(4))) float f32x4;
typedef __attribute__((ext_vector_type(16))) float f32x16;

#define DEVI static __device__ __forceinline__

DEVI u16 f2bf(float f) {
  union { float f; u32 u; } v; v.f = f;
  u32 r = v.u + 0x7FFFu + ((v.u >> 16) & 1u);
  return (u16)(r >> 16);
}

DEVI u32 pack2bf(float lo, float hi) {
  return (u32)f2bf(lo) | ((u32)f2bf(hi) << 16);
}

// fast pack: round-half-up bf16 pair via v_perm_b32 (3 VALU ops / 2 elements)
DEVI u32 pack2bf_fast(float lo, float hi) {
  union { float f; u32 u; } a, b;
  a.f = lo; b.f = hi;
  return __builtin_amdgcn_perm(b.u + 0x8000u, a.u + 0x8000u, 0x07060302u);
}

// single-instruction RNE bf16 pair pack
DEVI u32 cvtpk(float lo, float hi) {
  u32 r;
  asm("v_cvt_pk_bf16_f32 %0, %1, %2" : "=v"(r) : "v"(lo), "v"(hi));
  return r;
}

// lane[0:31] of b <-> lane[32:63] of a  (both updated)
DEVI void swap32(u32& a, u32& b) {
  asm("v_permlane32_swap_b32 %0, %1" : "+v"(a), "+v"(b));
}

DEVI void gload_lds16(const u16* g, u16* l) {
  __builtin_amdgcn_global_load_lds((const __attribute__((address_space(1))) void*)g,
                                   (__attribute__((address_space(3))) void*)l, 16, 0, 0);
}

// chunk swizzle: 16B chunk 'chunk' of row r lives at slot chunk^(r&7)^((r>>3)&3).
DEVI int sw8(int chunk, int r) { return ((chunk ^ (r & 7) ^ ((r >> 3) & 3)) * 8); }

// ---------------- prep: weight transpose f32->bf16 (4 weights) + input cvt f32->bf16 (3 inputs)
__global__ __launch_bounds__(256) void prep(const float* __restrict__ wq, const float* __restrict__ wk,
                                            const float* __restrict__ wv, const float* __restrict__ wo,
                                            u16* __restrict__ wqT, u16* __restrict__ wkT,
                                            u16* __restrict__ wvT, u16* __restrict__ woT,
                                            const float* __restrict__ xq, const float* __restrict__ xk,
                                            const float* __restrict__ xv,
                                            u16* __restrict__ qb, u16* __restrict__ kb,
                                            u16* __restrict__ vb) {
  const int bid = blockIdx.x;
  const int t = threadIdx.x;
  if (bid < 1024) {
    int z = bid >> 8, tl = bid & 255;
    const float* src = z == 0 ? wq : z == 1 ? wk : z == 2 ? wv : wo;
    u16* dst = z == 0 ? wqT : z == 1 ? wkT : z == 2 ? wvT : woT;
    __shared__ float tile[32][33];
    int tx = t & 31, ty = t >> 5;
    int bx = (tl & 15) * 32, by = (tl >> 4) * 32;
#pragma unroll
    for (int i = 0; i < 32; i += 8)
      tile[ty + i][tx] = src[(size_t)(by + ty + i) * 512 + bx + tx];
    __syncthreads();
#pragma unroll
    for (int i = 0; i < 32; i += 8)
      dst[(size_t)(bx + ty + i) * 512 + by + tx] = f2bf(tile[tx][ty + i]);
  } else {
    int cid = bid - 1024;
    int which = cid >> 11, chunk = cid & 2047;
    const float* src = which == 0 ? xq : which == 1 ? xk : xv;
    u16* dst = which == 0 ? qb : which == 1 ? kb : vb;
    size_t base = (size_t)chunk * 2048 + t * 8;
    float4 f0 = *(const float4*)(src + base);
    float4 f1 = *(const float4*)(src + base + 4);
    uint4 pk;
    pk.x = pack2bf_fast(f0.x, f0.y);
    pk.y = pack2bf_fast(f0.z, f0.w);
    pk.z = pack2bf_fast(f1.x, f1.y);
    pk.w = pack2bf_fast(f1.z, f1.w);
    *(uint4*)(dst + base) = pk;
  }
}

// ---------------- fused QKV GEMM, 64x128 tile, counted-vmcnt double-buffer ----------------
// v3: 2 LDS buffers (48KB -> 3 blocks/CU); stage(it+1) then vmcnt(6)+barrier (next tile's
// 6 loads stay in flight across compute — no full drain until tail). Second barrier is a
// raw s_barrier (memory-clobber asm): orders this iter's ds_reads vs next iter's staging,
// without draining VMEM. Removes 8x per-kernel exposed-load-latency drains (m218 lever).
__global__ __launch_bounds__(256, 3) void gemm_qkv(
    const u16* __restrict__ A0, const u16* __restrict__ A1, const u16* __restrict__ A2,
    const u16* __restrict__ W0, const u16* __restrict__ W1, const u16* __restrict__ W2,
    const float* __restrict__ b0, const float* __restrict__ b1, const float* __restrict__ b2,
    u16* __restrict__ oq, u16* __restrict__ ok, u16* __restrict__ vt, float qscale) {
  const int z = blockIdx.z;
  const u16* A = z == 0 ? A0 : z == 1 ? A1 : A2;
  const u16* WT = z == 0 ? W0 : z == 1 ? W1 : W2;
  const float* bias = z == 0 ? b0 : z == 1 ? b1 : b2;
  const float sc = z == 0 ? qscale : 1.0f;

  __shared__ __align__(16) u16 As[2][64 * 64];   // 2 x 8 KB
  __shared__ __align__(16) u16 Bs[2][128 * 64];  // 2 x 16 KB
  const int t = threadIdx.x;
  const int w = t >> 6, lane = t & 63, quad = lane >> 4, li = lane & 15;
  const int m0 = blockIdx.x * 64, n0 = blockIdx.y * 128;
  const int wm = (w >> 1) * 32, wn = (w & 1) * 64;

  f32x4 zv = {0.f, 0.f, 0.f, 0.f};
  f32x4 acc[2][4];
#pragma unroll
  for (int mi = 0; mi < 2; mi++)
#pragma unroll
    for (int ni = 0; ni < 4; ni++) acc[mi][ni] = zv;

#define STAGE_Q(buf, it)                                                                     \
  do {                                                                                       \
    const int k0_ = (it) * 64;                                                               \
    _Pragma("unroll") for (int p = 0; p < 2; p++) {                                          \
      int s = p * 256 + t;                                                                   \
      int r = s >> 3, c8 = s & 7;                                                            \
      gload_lds16(A + (size_t)(m0 + r) * 512 + k0_ + sw8(c8, r),                             \
                  &As[buf][(p * 256 + w * 64) * 8]);                                         \
    }                                                                                        \
    _Pragma("unroll") for (int p = 0; p < 4; p++) {                                          \
      int s = p * 256 + t;                                                                   \
      int r = s >> 3, c8 = s & 7;                                                            \
      gload_lds16(WT + (size_t)(n0 + r) * 512 + k0_ + sw8(c8, r),                            \
                  &Bs[buf][(p * 256 + w * 64) * 8]);                                         \
    }                                                                                        \
  } while (0)

  STAGE_Q(0, 0);
#pragma unroll 1
  for (int it = 0; it < 8; it++) {
    if (it < 7) {
      STAGE_Q((it + 1) & 1, it + 1);
      asm volatile("s_waitcnt vmcnt(6)" ::: "memory");  // tile it landed; it+1 in flight
    } else {
      asm volatile("s_waitcnt vmcnt(0)" ::: "memory");
    }
    __builtin_amdgcn_s_barrier();
    const u16* Asb = &As[it & 1][0];
    const u16* Bsb = &Bs[it & 1][0];
#pragma unroll
    for (int ks = 0; ks < 2; ks++) {
      short8 af[2], bf[4];
#pragma unroll
      for (int mi = 0; mi < 2; mi++) {
        int r = wm + mi * 16 + li;
        af[mi] = *(const short8*)&Asb[r * 64 + sw8(ks * 4 + quad, r)];
      }
#pragma unroll
      for (int ni = 0; ni < 4; ni++) {
        int r = wn + ni * 16 + li;
        bf[ni] = *(const short8*)&Bsb[r * 64 + sw8(ks * 4 + quad, r)];
      }
#pragma unroll
      for (int mi = 0; mi < 2; mi++)
#pragma unroll
        for (int ni = 0; ni < 4; ni++)
          acc[mi][ni] = __builtin_amdgcn_mfma_f32_16x16x32_bf16(af[mi], bf[ni], acc[mi][ni], 0, 0, 0);
    }
    // raw barrier (no vmcnt drain): all waves' reads of buf(it&1) done before next STAGE
    asm volatile("s_barrier" ::: "memory");
  }
#undef STAGE_Q

  float bv[4];
#pragma unroll
  for (int ni = 0; ni < 4; ni++) bv[ni] = bias[n0 + wn + ni * 16 + li];

  if (z < 2) {
    u16* out = z == 0 ? oq : ok;
#pragma unroll
    for (int mi = 0; mi < 2; mi++)
#pragma unroll
      for (int ni = 0; ni < 4; ni++)
#pragma unroll
        for (int r = 0; r < 4; r++) {
          int row = m0 + wm + mi * 16 + quad * 4 + r;
          int col = n0 + wn + ni * 16 + li;
          out[(size_t)row * 512 + col] = f2bf((acc[mi][ni][r] + bv[ni]) * sc);
        }
  } else {
    // V: write directly in VT [b, h, d, 2048] layout
#pragma unroll
    for (int mi = 0; mi < 2; mi++)
#pragma unroll
      for (int ni = 0; ni < 4; ni++) {
        int col = n0 + wn + ni * 16 + li;
        int h = col >> 6, dd = col & 63;
        int row0 = m0 + wm + mi * 16 + quad * 4;
        int bb = row0 >> 11, l0 = row0 & 2047;
        uint2 dw;
        dw.x = pack2bf(acc[mi][ni][0] + bv[ni], acc[mi][ni][1] + bv[ni]);
        dw.y = pack2bf(acc[mi][ni][2] + bv[ni], acc[mi][ni][3] + bv[ni]);
        *(uint2*)&vt[((size_t)((bb * 8 + h) * 64 + dd)) * 2048 + l0] = dw;
      }
  }
}

// ---------------- final projection GEMM, 64x64 tile, counted-vmcnt double-buffer ----------------
// v3: 2 LDS buffers (32KB -> 5 blocks/CU); vmcnt(4) steady-state, raw barrier after compute.
__global__ __launch_bounds__(256, 5) void gemm_out(const u16* __restrict__ A,
                                                   const u16* __restrict__ WT,
                                                   const float* __restrict__ bias,
                                                   float* __restrict__ out) {
  __shared__ __align__(16) u16 As[2][64 * 64];  // 2 x 8 KB
  __shared__ __align__(16) u16 Bs[2][64 * 64];  // 2 x 8 KB
  const int t = threadIdx.x;
  const int w = t >> 6, lane = t & 63, quad = lane >> 4, li = lane & 15;
  const int m0 = blockIdx.x * 64, n0 = blockIdx.y * 64;
  const int wm = (w >> 1) * 32, wn = (w & 1) * 32;

  f32x4 zv = {0.f, 0.f, 0.f, 0.f};
  f32x4 acc[2][2];
#pragma unroll
  for (int mi = 0; mi < 2; mi++)
#pragma unroll
    for (int ni = 0; ni < 2; ni++) acc[mi][ni] = zv;

#define STAGE_O(buf, it)                                                                     \
  do {                                                                                       \
    const int k0_ = (it) * 64;                                                               \
    _Pragma("unroll") for (int p = 0; p < 2; p++) {                                          \
      int s = p * 256 + t;                                                                   \
      int r = s >> 3, c8 = s & 7;                                                            \
      gload_lds16(A + (size_t)(m0 + r) * 512 + k0_ + sw8(c8, r),                             \
                  &As[buf][(p * 256 + w * 64) * 8]);                                         \
    }                                                                                        \
    _Pragma("unroll") for (int p = 0; p < 2; p++) {                                          \
      int s = p * 256 + t;                                                                   \
      int r = s >> 3, c8 = s & 7;                                                            \
      gload_lds16(WT + (size_t)(n0 + r) * 512 + k0_ + sw8(c8, r),                            \
                  &Bs[buf][(p * 256 + w * 64) * 8]);                                         \
    }                                                                                        \
  } while (0)

  STAGE_O(0, 0);
#pragma unroll 1
  for (int it = 0; it < 8; it++) {
    if (it < 7) {
      STAGE_O((it + 1) & 1, it + 1);
      asm volatile("s_waitcnt vmcnt(4)" ::: "memory");  // tile it landed; it+1 in flight
    } else {
      asm volatile("s_waitcnt vmcnt(0)" ::: "memory");
    }
    __builtin_amdgcn_s_barrier();
    const u16* Asb = &As[it & 1][0];
    const u16* Bsb = &Bs[it & 1][0];
#pragma unroll
    for (int ks = 0; ks < 2; ks++) {
      short8 af[2], bf[2];
#pragma unroll
      for (int mi = 0; mi < 2; mi++) {
        int r = wm + mi * 16 + li;
        af[mi] = *(const short8*)&Asb[r * 64 + sw8(ks * 4 + quad, r)];
      }
#pragma unroll
      for (int ni = 0; ni < 2; ni++) {
        int r = wn + ni * 16 + li;
        bf[ni] = *(const short8*)&Bsb[r * 64 + sw8(ks * 4 + quad, r)];
      }
#pragma unroll
      for (int mi = 0; mi < 2; mi++)
#pragma unroll
        for (int ni = 0; ni < 2; ni++)
          acc[mi][ni] = __builtin_amdgcn_mfma_f32_16x16x32_bf16(af[mi], bf[ni], acc[mi][ni], 0, 0, 0);
    }
    asm volatile("s_barrier" ::: "memory");
  }
#undef STAGE_O

  float bv[2];
#pragma unroll
  for (int ni = 0; ni < 2; ni++) bv[ni] = bias[n0 + wn + ni * 16 + li];
#pragma unroll
  for (int mi = 0; mi < 2; mi++)
#pragma unroll
    for (int ni = 0; ni < 2; ni++)
#pragma unroll
      for (int r = 0; r < 4; r++) {
        int row = m0 + wm + mi * 16 + quad * 4 + r;
        int col = n0 + wn + ni * 16 + li;
        out[(size_t)row * 512 + col] = acc[mi][ni][r] + bv[ni];
      }
}

// ---------------- attention: EXACT R5/R8/R10 version (known-good, 50.3 us) ----------------
// R11 lesson: LDS-free per-lane gathers (32-line split transactions) collapse MfmaUtil
// to 10% — fragment layouts REQUIRE LDS staging. This version is frozen.
__global__ __launch_bounds__(256, 2) void attn(const u16* Qp,
                                               const u16* __restrict__ Kp,
                                               const u16* __restrict__ VT,
                                               u16* ctx) {
  __shared__ __align__(16) u16 Ks[4][64 * 64];  // [buf][kj][d] 32 KB
  __shared__ __align__(16) u16 Vs[4][64 * 64];  // [buf][d][kj] 32 KB
  const int t = threadIdx.x;
  const int w = t >> 6, lane = t & 63, qn = lane & 31, hi = lane >> 5;
  const int b = blockIdx.z, h = blockIdx.y;
  const int q0 = blockIdx.x * 128;
  const int qrow = q0 + w * 32 + qn;

  // Q fragments direct from global (one-time): B[k=d][n=q]
  short8 qf[4];
  {
    const u16* qg = Qp + (size_t)(b * 2048 + qrow) * 512 + h * 64 + hi * 8;
#pragma unroll
    for (int ks = 0; ks < 4; ks++) qf[ks] = *(const short8*)(qg + ks * 16);
  }

  f32x16 o[2];
#pragma unroll
  for (int dt = 0; dt < 2; dt++)
#pragma unroll
    for (int r = 0; r < 16; r++) o[dt][r] = 0.f;
  float lsum = 0.f;

  // staging geometry: thread t stages rows rs and rs+32, chunk cs (pre-swizzled source)
  const int rs = t >> 3, cs = t & 7;
  const u16* kbase = Kp + (size_t)(b * 2048) * 512 + h * 64;
  const u16* vbase = VT + ((size_t)((b * 8 + h) * 64)) * 2048;

#define STAGE(buf, k0v)                                                                     \
  do {                                                                                      \
    int r0_ = rs, r1_ = 32 + rs;                                                            \
    gload_lds16(kbase + (size_t)((k0v) + r0_) * 512 + sw8(cs, r0_), &Ks[buf][(w * 64) * 8]); \
    gload_lds16(vbase + (size_t)r0_ * 2048 + (k0v) + sw8(cs, r0_), &Vs[buf][(w * 64) * 8]); \
    gload_lds16(kbase + (size_t)((k0v) + r1_) * 512 + sw8(cs, r1_),                         \
                &Ks[buf][(256 + w * 64) * 8]);                                              \
    gload_lds16(vbase + (size_t)r1_ * 2048 + (k0v) + sw8(cs, r1_),                          \
                &Vs[buf][(256 + w * 64) * 8]);                                              \
  } while (0)

  STAGE(0, 0);
  STAGE(1, 64);

  for (int kt = 0; kt < 32; kt++) {
    if (kt < 30) {
      STAGE((kt + 2) & 3, (kt + 2) * 64);  // prefetch 2 tiles ahead
      asm volatile("s_waitcnt vmcnt(8)" ::: "memory");  // tile kt's loads done; kt+1/kt+2 in flight
    } else if (kt == 30) {
      asm volatile("s_waitcnt vmcnt(4)" ::: "memory");
    } else {
      asm volatile("s_waitcnt vmcnt(0)" ::: "memory");
    }
    __builtin_amdgcn_s_barrier();  // collective: tile kt fully in LDS; buf reuse safe

    const u16* Kc = &Ks[kt & 3][0];
    const u16* Vc = &Vs[kt & 3][0];

#pragma unroll
    for (int kjt = 0; kjt < 2; kjt++) {
      // S^T = K·Q^T : lane qn holds column q=qrow, rows kj = kjt*32 + (r&3)+8*(r>>2)+4*hi
      f32x16 st;
#pragma unroll
      for (int r = 0; r < 16; r++) st[r] = 0.f;
#pragma unroll
      for (int ks4 = 0; ks4 < 4; ks4++) {
        int m = kjt * 32 + qn;
        short8 ka = *(const short8*)&Kc[m * 64 + sw8(ks4 * 2 + hi, m)];
        st = __builtin_amdgcn_mfma_f32_32x32x16_bf16(ka, qf[ks4], st, 0, 0, 0);
      }

      // p = exp2(s); pack pairs to bf16 (RNE) in-register
      u32 pk[8];
#pragma unroll
      for (int i = 0; i < 8; i++) {
        float p0 = __builtin_amdgcn_exp2f(st[2 * i]);
        float p1 = __builtin_amdgcn_exp2f(st[2 * i + 1]);
        lsum += p0 + p1;
        pk[i] = cvtpk(p0, p1);
      }
      // cross-half exchange: lane qn / qn+32 hold complementary kj subsets of the same q.
      u32 a0 = pk[0], a2 = pk[2]; swap32(a0, a2);
      u32 a1 = pk[1], a3 = pk[3]; swap32(a1, a3);
      u32 c0 = pk[4], c2 = pk[6]; swap32(c0, c2);
      u32 c1 = pk[5], c3 = pk[7]; swap32(c1, c3);
      union { u32 u[4]; short8 s8; } pa, pb;
      pa.u[0] = a0; pa.u[1] = a1; pa.u[2] = a2; pa.u[3] = a3;  // kj slice kjt*2   (local 0..15)
      pb.u[0] = c0; pb.u[1] = c1; pb.u[2] = c2; pb.u[3] = c3;  // kj slice kjt*2+1 (local 16..31)

      // O^T += V^T · P^T
#pragma unroll
      for (int dt = 0; dt < 2; dt++) {
        int m = dt * 32 + qn;
        short8 vA = *(const short8*)&Vc[m * 64 + sw8(kjt * 4 + hi, m)];
        o[dt] = __builtin_amdgcn_mfma_f32_32x32x16_bf16(vA, pa.s8, o[dt], 0, 0, 0);
      }
#pragma unroll
      for (int dt = 0; dt < 2; dt++) {
        int m = dt * 32 + qn;
        short8 vB = *(const short8*)&Vc[m * 64 + sw8(kjt * 4 + 2 + hi, m)];
        o[dt] = __builtin_amdgcn_mfma_f32_32x32x16_bf16(vB, pb.s8, o[dt], 0, 0, 0);
      }
    }
  }
#undef STAGE

  // epilogue: lane qn holds all 64 d-values of q=qrow (split across hi for d-subsets);
  // normalize by this lane's own full-row sum and store final bf16 ctx[q][h*64+d].
  float l = lsum + __shfl_xor(lsum, 32);
  float inv = 1.0f / l;
  u16* dst = ctx + (size_t)(b * 2048 + qrow) * 512 + h * 64;
#pragma unroll
  for (int dt = 0; dt < 2; dt++)
#pragma unroll
    for (int j = 0; j < 4; j++) {
      // r = j*4 + rr (rr=0..3) -> d = dt*32 + 8*j + 4*hi + rr (4 contiguous d)
      int d0 = dt * 32 + 8 * j + 4 * hi;
      uint2 dw;
      dw.x = pack2bf(o[dt][j * 4 + 0] * inv, o[dt][j * 4 + 1] * inv);
      dw.y = pack2bf(o[dt][j * 4 + 2] * inv, o[dt][j * 4 + 3] * inv);
      *(uint2*)(dst + d0) = dw;
    }
}

extern "C" void kernel_launch(void* const* d_in, const int* in_sizes, int n_in,
                              void* d_out, int out_size, void* d_ws, size_t ws_size,
                              hipStream_t stream) {
  const float* query = (const float*)d_in[0];
  const float* key_ = (const float*)d_in[1];
  const float* value = (const float*)d_in[2];
  const float* wq = (const float*)d_in[3];
  const float* bq = (const float*)d_in[4];
  const float* wk = (const float*)d_in[5];
  const float* bk = (const float*)d_in[6];
  const float* wv = (const float*)d_in[7];
  const float* bv = (const float*)d_in[8];
  const float* wo = (const float*)d_in[9];
  const float* bo = (const float*)d_in[10];

  char* ws = (char*)d_ws;
  const size_t SZ_W = (size_t)512 * 512 * 2;   // 512 KB
  const size_t SZ_X = (size_t)8192 * 512 * 2;  // 8 MB
  u16* wqT = (u16*)(ws);
  u16* wkT = (u16*)(ws + SZ_W);
  u16* wvT = (u16*)(ws + 2 * SZ_W);
  u16* woT = (u16*)(ws + 3 * SZ_W);
  u16* Qp = (u16*)(ws + 4 * SZ_W);
  u16* Kp = (u16*)(ws + 4 * SZ_W + SZ_X);
  u16* VTp = (u16*)(ws + 4 * SZ_W + 2 * SZ_X);
  u16* Qb = (u16*)(ws + 4 * SZ_W + 3 * SZ_X);  // bf16 pre-converted inputs
  u16* Kb = (u16*)(ws + 4 * SZ_W + 4 * SZ_X);
  u16* Vb = (u16*)(ws + 4 * SZ_W + 5 * SZ_X);
  u16* ctx = Qp;  // attn writes final ctx in-place over Qp (per-lane-safe aliasing)

  const float C1 = 0.125f * 1.44269504088896f;  // softmax scale * log2(e), folded into Q

  prep<<<dim3(7168), 256, 0, stream>>>(wq, wk, wv, wo, wqT, wkT, wvT, woT,
                                       query, key_, value, Qb, Kb, Vb);
  gemm_qkv<<<dim3(128, 4, 3), 256, 0, stream>>>(Qb, Kb, Vb, wqT, wkT, wvT,
                                                bq, bk, bv, Qp, Kp, VTp, C1);
  attn<<<dim3(16, 8, 4), 256, 0, stream>>>(Qp, Kp, VTp, ctx);
  gemm_out<<<dim3(128, 8), 256, 0, stream>>>(ctx, woT, bo, (float*)d_out);
}